// Round 8
// baseline (135.448 us; speedup 1.0000x reference)
//
#include <hip/hip_runtime.h>
#include <hip/hip_bf16.h>

// QuantizedConv2d: B=8, Cin=Cout=320, H=W=64, K=3, stride=1, pad=1.
// out = scale[co] * conv_zp_padded_int8(x_int, W) + bias_eff[co]
// bias_eff[co] = bias[co] - scale[co]*zp*sum(W[co]); x padded with zp byte.

typedef int v4i __attribute__((ext_vector_type(4)));

typedef const unsigned int __attribute__((address_space(1)))* gas_uptr;
typedef unsigned int __attribute__((address_space(3)))* las_uptr;

#define B_   8
#define CIN  320
#define COUT 320
#define H_   64
#define W_   64
#define HW_  4096
#define HP   66
#define WP   66
#define XPAD_BYTES (B_*HP*WP*CIN)
#define W8_BYTES (COUT*9*CIN)

// ---------------------------------------------------------------------------
// Kernel 1: weight repack int32 [O][I][3][3] -> FRAGMENT-LINEAR int8 layout
//   w8[coT(20)][tap(9)][chunk(5)][lane(64)][16B],  lane = q*16 + colc,
//   holding bytes w_orig[co = coT*16+colc][tap][ci = chunk*64 + q*16 .. +16].
// One B-fragment wave-load = one contiguous aligned 1KiB burst. (unchanged)
__global__ __launch_bounds__(256) void repack_bias_kernel(const int* __restrict__ wint,
                                                          unsigned char* __restrict__ w8,
                                                          const float* __restrict__ wsum,
                                                          const float* __restrict__ scale,
                                                          const float* __restrict__ bias,
                                                          const float* __restrict__ zp_p,
                                                          float* __restrict__ be) {
    int j = blockIdx.x * 256 + threadIdx.x;     // < 230,400 dwords
    if (j < COUT) {
        float s = 0.f;
        #pragma unroll
        for (int tp = 0; tp < 9; ++tp) s += wsum[j*9 + tp];
        be[j] = bias[j] - scale[j] * zp_p[0] * s;
    }
    int co  = j / 720;
    int r   = j - co * 720;                     // tap*80 + d
    int tap = r / 80;
    int d   = r - tap * 80;
    int ci  = d * 4;
    const int* base = wint + (co * CIN + ci) * 9 + tap;
    unsigned b0 = (unsigned)(base[0]  & 0xFF);
    unsigned b1 = (unsigned)(base[9]  & 0xFF);
    unsigned b2 = (unsigned)(base[18] & 0xFF);
    unsigned b3 = (unsigned)(base[27] & 0xFF);
    unsigned dword = b0 | (b1 << 8) | (b2 << 16) | (b3 << 24);

    int coT   = co >> 4;
    int colc  = co & 15;
    int chunk = ci >> 6;
    int q     = (ci >> 4) & 3;
    int dw    = (ci >> 2) & 3;
    int lane  = q * 16 + colc;
    int idx   = (((coT * 9 + tap) * 5 + chunk) * 64 + lane) * 4 + dw;
    ((unsigned*)w8)[idx] = dword;
}

// ---------------------------------------------------------------------------
// Kernel 2: quantize + pad (register transpose; LDS dword writes stride 81).
// (unchanged)
__global__ __launch_bounds__(256) void quant_pad_kernel(const float* __restrict__ x,
                                                        unsigned char* __restrict__ xpad,
                                                        const float* __restrict__ inv_p,
                                                        const float* __restrict__ zp_p) {
    __shared__ __align__(16) unsigned lds[64 * 81];
    int bid = blockIdx.x;
    int b  = bid / HP;
    int ph = bid - b * HP;
    int t  = threadIdx.x;
    float inv = inv_p[0];
    float zp  = zp_p[0];
    int zpi = (int)rintf(zp);
    unsigned zd = ((unsigned)(zpi & 0xFF)) * 0x01010101u;

    unsigned* rowbase = (unsigned*)(xpad + (size_t)((b * HP + ph) * WP) * CIN);

    if (ph == 0 || ph == HP - 1) {
        for (int j = t; j < WP * CIN / 4; j += 256) rowbase[j] = zd;
        return;
    }
    int h = ph - 1;
    const float* xrow = x + (size_t)b * CIN * H_ * W_ + h * W_;
    int wq = t & 15;
    int cg = t >> 4;
    #pragma unroll
    for (int i = 0; i < 5; ++i) {
        int ci0 = i * 64 + cg * 4;
        float4 f[4];
        #pragma unroll
        for (int jj = 0; jj < 4; ++jj)
            f[jj] = *(const float4*)(xrow + (size_t)(ci0 + jj) * HW_ + wq * 4);
        #pragma unroll
        for (int k = 0; k < 4; ++k) {
            unsigned d = 0;
            #pragma unroll
            for (int jj = 0; jj < 4; ++jj) {
                float v = (&f[jj].x)[k];
                float q = rintf(v * inv) + zp;
                q = fminf(fmaxf(q, -128.0f), 127.0f);
                int qi = (int)q;
                d |= ((unsigned)(qi & 0xFF)) << (8 * jj);
            }
            lds[(wq * 4 + k) * 81 + (ci0 >> 2)] = d;
        }
    }
    __syncthreads();
    if (t < 80)            rowbase[t] = zd;
    else if (t < 160)      rowbase[65 * 80 + (t - 80)] = zd;
    for (int j = t; j < 64 * 80; j += 256) {
        int p = j / 80;
        int d = j - p * 80;
        rowbase[80 + j] = lds[p * 81 + d];
    }
}

// ---------------------------------------------------------------------------
// Kernel 3: implicit-GEMM conv -- modulo-3 register banks + counted-vmcnt
// chunk barrier. Block tile 256(M) x 80(N), 4 waves = 4 M-quarters;
// wave = 64x80 = 4x5 of 16x16x64 i8. 3-deep B / 3-deep A pipeline.
//
// Round-7 post-mortem: latency-depth, setprio, and B-L1-dedupe all gave
// ~1us -- the stall is not a single latency term. Two mechanical defects
// fixed here:
// (1) __syncthreads() at chunk end = s_waitcnt vmcnt(0): force-drains the
//     cross-chunk B prefetches issued at taps 6-8 (~400cy L2 latency, all
//     waves idle, 5x/block). Steady state has EXACTLY 15 outstanding loads
//     at the barrier (the 3 cross-chunk B fragments; staging is older and
//     already drained by tap8's compiler-inserted B-wait), so the correct
//     barrier is s_waitcnt vmcnt(15) + raw s_barrier -- T4, never drain.
//     Prologue reordered (staging FIRST, then B prefetch) for the same
//     invariant at the first barrier.
// (2) rotating regs (bC<-bN<-bN2) forced real v_mov chains at chunk-loop
//     boundaries. Depth 3 divides 9 taps -> modulo-3 BANKS bB[tp%3]/
//     aB[tp%3], all indices compile-time: zero rotation code, fixed regs,
//     and each bank reload naturally sits after its MFMA cluster (WAR),
//     spreading load issue across the tap.
#define CHUNK_SLOTS 1584           // 6 rows * 66 cols * 4 sub-chunks
#define ROUNDS 7                   // ceil(1584 / 256)
#define BUF_BYTES (ROUNDS * 256 * 16)   // 28,672 B per buffer (25,344 used)

// One chunk's compute. LAST_ must be a literal 0/1 so every guard below is
// compile-time (tp is unroll-constant): bank indices stay static (rule #20).
#define CHUNK_BODY(c_, LAST_)                                                   \
{                                                                               \
    const int c__ = (c_);                                                       \
    const unsigned char* ab = Al + (c__ & 1) * BUF_BYTES;                       \
    /* A banks: taps 0,1,2 (all kh=0, kw=0/1/2). Only exposed ds_reads. */      \
    _Pragma("unroll")                                                           \
    for (int k = 0; k < 3; ++k)                                                 \
        _Pragma("unroll")                                                       \
        for (int mi = 0; mi < 4; ++mi)                                          \
            aB[k][mi] = *(const v4i*)(ab + wm * 4224 + aoffs[k][mi]);           \
    _Pragma("unroll")                                                           \
    for (int tp = 0; tp < 9; ++tp) {                                            \
        const int bank = tp % 3;                                                \
        if (!LAST_ && tp == 0) {    /* stage chunk c+1: oldest vmem of chunk */ \
            unsigned char* dst = Al + ((c__ + 1) & 1) * BUF_BYTES;              \
            int cio = (c__ + 1) * 64;                                           \
            _Pragma("unroll")                                                   \
            for (int r = 0; r < ROUNDS; ++r)                                    \
                __builtin_amdgcn_global_load_lds(                               \
                    (gas_uptr)(const void*)(xpad + srcoff[r] + cio),            \
                    (las_uptr)(dst + r * 4096 + t * 16), 16, 0, 0);             \
        }                                                                       \
        /* consume bank (T5 priority through the MFMA cluster) */               \
        __builtin_amdgcn_s_setprio(1);                                          \
        _Pragma("unroll")                                                       \
        for (int mi = 0; mi < 4; ++mi)                                          \
            _Pragma("unroll")                                                   \
            for (int ni = 0; ni < 5; ++ni)                                      \
                acc[mi][ni] = __builtin_amdgcn_mfma_i32_16x16x64_i8(            \
                    aB[bank][mi], bB[bank][ni], acc[mi][ni], 0, 0, 0);          \
        __builtin_amdgcn_s_setprio(0);                                          \
        /* refill bank: tp<6 -> tap tp+3 of this chunk; tp>=6 -> taps 0..2 */   \
        /* of next chunk (stay in flight across the counted barrier).      */   \
        if (tp < 6) {                                                           \
            _Pragma("unroll")                                                   \
            for (int ni = 0; ni < 5; ++ni)                                      \
                bB[bank][ni] = *(const v4i*)(bbase[ni] + ((tp + 3) * 5 + c__) * 1024);\
            int tn  = tp + 3;                                                   \
            int kh2 = tn / 3;                                                   \
            int kw2 = tn - kh2 * 3;                                             \
            _Pragma("unroll")                                                   \
            for (int mi = 0; mi < 4; ++mi)                                      \
                aB[bank][mi] = *(const v4i*)(ab + (wm + kh2) * 4224 + aoffs[kw2][mi]);\
        } else if (!LAST_) {                                                    \
            _Pragma("unroll")                                                   \
            for (int ni = 0; ni < 5; ++ni)                                      \
                bB[bank][ni] = *(const v4i*)(bbase[ni] + ((tp - 6) * 5 + (c__ + 1)) * 1024);\
        }                                                                       \
    }                                                                           \
}

__global__ __launch_bounds__(256, 2) void conv_gemm_kernel(const unsigned char* __restrict__ xpad,
                                                           const unsigned char* __restrict__ w8,
                                                           const float* __restrict__ scale,
                                                           const float* __restrict__ be,
                                                           float* __restrict__ out) {
    __shared__ __align__(16) unsigned char Al[2 * BUF_BYTES];   // 57,344 B

    int t    = threadIdx.x;
    int lane = t & 63;
    int wave = t >> 6;
    int wm   = wave;               // M quarter (64 pixels each); all waves share N
    int m0   = blockIdx.x * 256;   // 4 image rows of one batch image
    int n0   = blockIdx.y * 80;
    int b0   = m0 >> 12;
    int h0   = (m0 & 4095) >> 6;   // first output row of this 4-row tile

    // --- staging source offsets: slot = r*256+t -> (R,C,ql); source sub-chunk
    //     pre-swizzled: qs = ql ^ ((C>>1)&3). Slots >= 1584 clamp to slot 0
    //     (dup fetch = L1 hit; garbage lands in dead LDS tail 25344..28671).
    int srcoff[ROUNDS];
    #pragma unroll
    for (int r = 0; r < ROUNDS; ++r) {
        int slot = r * 256 + t;
        if (slot >= CHUNK_SLOTS) slot = 0;
        int R   = slot / 264;                 // 66 cols * 4 sub-chunks per row
        int rem = slot - R * 264;
        int C   = rem >> 2;
        int ql  = rem & 3;
        int qs  = ql ^ ((C >> 1) & 3);
        srcoff[r] = ((b0 * HP + h0 + R) * WP + C) * CIN + qs * 16;
    }

    int colc = lane & 15;
    int q    = lane >> 4;

    // --- A fragment LDS offsets (per kw, per mi); row term (wm+kh)*4224 added
    //     at use (wm 0..3, kh 0..2 -> rows 0..5). Phase-uniform swizzle:
    //     within any 16-lane quarter-wave, slot-group = 4(C&1) + q^((C>>1)&3)
    //     covers all 8 bank-groups exactly twice.
    int aoffs[3][4];
    #pragma unroll
    for (int kw = 0; kw < 3; ++kw)
        #pragma unroll
        for (int mi = 0; mi < 4; ++mi) {
            int C = mi * 16 + colc + kw;
            aoffs[kw][mi] = C * 64 + ((q ^ ((C >> 1) & 3)) * 16);
        }

    // --- B fragment base pointers: fragment-linear w8, one contiguous 1KiB
    //     per (coT, tap, chunk). IDENTICAL across the block's 4 waves.
    const unsigned char* bbase[5];
    int coT0 = n0 >> 4;
    #pragma unroll
    for (int ni = 0; ni < 5; ++ni)
        bbase[ni] = w8 + (size_t)(coT0 + ni) * (45 * 1024) + lane * 16;

    v4i acc[4][5];
    v4i zero = {0, 0, 0, 0};
    #pragma unroll
    for (int mi = 0; mi < 4; ++mi)
        #pragma unroll
        for (int ni = 0; ni < 5; ++ni) acc[mi][ni] = zero;

    // --- prologue: staging FIRST (oldest in vmcnt FIFO), then B banks for
    //     taps 0/1/2 -- so the counted barrier below leaves B in flight.
    v4i bB[3][5], aB[3][4];
    #pragma unroll
    for (int r = 0; r < ROUNDS; ++r)
        __builtin_amdgcn_global_load_lds((gas_uptr)(const void*)(xpad + srcoff[r]),
                                         (las_uptr)(Al + r * 4096 + t * 16), 16, 0, 0);
    #pragma unroll
    for (int k = 0; k < 3; ++k)
        #pragma unroll
        for (int ni = 0; ni < 5; ++ni)
            bB[k][ni] = *(const v4i*)(bbase[ni] + (k * 5) * 1024);

    // counted barrier: wait staging (7 oldest) only; 15 B loads stay in flight.
    asm volatile("s_waitcnt vmcnt(15)" ::: "memory");
    __builtin_amdgcn_s_barrier();

    #pragma unroll 1
    for (int c = 0; c < 4; ++c) {
        CHUNK_BODY(c, 0)
        // Steady state at this point: outstanding vmem = 15 cross-chunk B
        // loads (taps 6-8); staging (issued tap 0) already drained by tap 8's
        // compiler-inserted B-wait. vmcnt(15) is therefore ~free and the B
        // prefetch pipeline survives the barrier (T4: never drain to 0).
        asm volatile("s_waitcnt vmcnt(15)" ::: "memory");
        __builtin_amdgcn_s_barrier();
    }
    CHUNK_BODY(4, 1)       // peeled: no staging, no cross-chunk B, static guards

    // Epilogue: C/D layout col = lane&15 (co), row = q*4 + reg (pixel).
    #pragma unroll
    for (int ni = 0; ni < 5; ++ni) {
        int co = n0 + ni * 16 + colc;
        float s  = scale[co];
        float bz = be[co];
        #pragma unroll
        for (int mi = 0; mi < 4; ++mi) {
            int pix = m0 + wm * 64 + mi * 16 + q * 4;
            int bb2 = pix >> 12;
            int hw  = pix & 4095;
            v4i v = acc[mi][ni];
            float4 o;
            o.x = s * (float)v.x + bz;
            o.y = s * (float)v.y + bz;
            o.z = s * (float)v.z + bz;
            o.w = s * (float)v.w + bz;
            *(float4*)(out + (size_t)(bb2 * COUT + co) * HW_ + hw) = o;
        }
    }
}

// ---------------------------------------------------------------------------
extern "C" void kernel_launch(void* const* d_in, const int* in_sizes, int n_in,
                              void* d_out, int out_size, void* d_ws, size_t ws_size,
                              hipStream_t stream) {
    const float* x     = (const float*)d_in[0];
    const int*   wint  = (const int*)d_in[1];
    const float* wsum  = (const float*)d_in[2];
    const float* scale = (const float*)d_in[3];
    const float* inv_p = (const float*)d_in[4];
    const float* zp_p  = (const float*)d_in[5];
    const float* bias  = (const float*)d_in[6];
    float* out = (float*)d_out;

    unsigned char* xpad = (unsigned char*)d_ws;
    unsigned char* w8   = xpad + XPAD_BYTES;
    float*         be   = (float*)(w8 + W8_BYTES);

    repack_bias_kernel<<<(COUT * 720) / 256, 256, 0, stream>>>(wint, w8, wsum, scale, bias, zp_p, be);
    quant_pad_kernel<<<B_ * HP, 256, 0, stream>>>(x, xpad, inv_p, zp_p);

    dim3 grid((B_ * H_ * W_) / 256, COUT / 80);       // 128 x 4 = 512 blocks
    conv_gemm_kernel<<<grid, 256, 0, stream>>>(xpad, w8, scale, be, out);
}

// Round 10
// 133.501 us; speedup vs baseline: 1.0146x; 1.0146x over previous
//
#include <hip/hip_runtime.h>
#include <hip/hip_bf16.h>

// QuantizedConv2d: B=8, Cin=Cout=320, H=W=64, K=3, stride=1, pad=1.
// out = scale[co] * conv_zp_padded_int8(x_int, W) + bias_eff[co]
// bias_eff[co] = bias[co] - scale[co]*zp*sum(W[co]); x padded with zp byte.

typedef int v4i __attribute__((ext_vector_type(4)));

typedef const unsigned int __attribute__((address_space(1)))* gas_uptr;
typedef unsigned int __attribute__((address_space(3)))* las_uptr;

#define B_   8
#define CIN  320
#define COUT 320
#define H_   64
#define W_   64
#define HW_  4096
#define HP   66
#define WP   66
#define XPAD_BYTES (B_*HP*WP*CIN)
#define W8_BYTES (COUT*9*CIN)

#define SGB __builtin_amdgcn_sched_group_barrier   // 0x8=MFMA 0x20=VMEM_READ 0x100=DS_READ

// ---------------------------------------------------------------------------
// Kernel 1: weight repack int32 [O][I][3][3] -> FRAGMENT-LINEAR int8 layout
//   w8[coT(20)][tap(9)][chunk(5)][lane(64)][16B],  lane = q*16 + colc.
// One B-fragment wave-load = one contiguous aligned 1KiB burst. (unchanged)
__global__ __launch_bounds__(256) void repack_bias_kernel(const int* __restrict__ wint,
                                                          unsigned char* __restrict__ w8,
                                                          const float* __restrict__ wsum,
                                                          const float* __restrict__ scale,
                                                          const float* __restrict__ bias,
                                                          const float* __restrict__ zp_p,
                                                          float* __restrict__ be) {
    int j = blockIdx.x * 256 + threadIdx.x;     // < 230,400 dwords
    if (j < COUT) {
        float s = 0.f;
        #pragma unroll
        for (int tp = 0; tp < 9; ++tp) s += wsum[j*9 + tp];
        be[j] = bias[j] - scale[j] * zp_p[0] * s;
    }
    int co  = j / 720;
    int r   = j - co * 720;                     // tap*80 + d
    int tap = r / 80;
    int d   = r - tap * 80;
    int ci  = d * 4;
    const int* base = wint + (co * CIN + ci) * 9 + tap;
    unsigned b0 = (unsigned)(base[0]  & 0xFF);
    unsigned b1 = (unsigned)(base[9]  & 0xFF);
    unsigned b2 = (unsigned)(base[18] & 0xFF);
    unsigned b3 = (unsigned)(base[27] & 0xFF);
    unsigned dword = b0 | (b1 << 8) | (b2 << 16) | (b3 << 24);

    int coT   = co >> 4;
    int colc  = co & 15;
    int chunk = ci >> 6;
    int q     = (ci >> 4) & 3;
    int dw    = (ci >> 2) & 3;
    int lane  = q * 16 + colc;
    int idx   = (((coT * 9 + tap) * 5 + chunk) * 64 + lane) * 4 + dw;
    ((unsigned*)w8)[idx] = dword;
}

// ---------------------------------------------------------------------------
// Kernel 2: quantize + pad (register transpose; LDS dword writes stride 81).
// (unchanged)
__global__ __launch_bounds__(256) void quant_pad_kernel(const float* __restrict__ x,
                                                        unsigned char* __restrict__ xpad,
                                                        const float* __restrict__ inv_p,
                                                        const float* __restrict__ zp_p) {
    __shared__ __align__(16) unsigned lds[64 * 81];
    int bid = blockIdx.x;
    int b  = bid / HP;
    int ph = bid - b * HP;
    int t  = threadIdx.x;
    float inv = inv_p[0];
    float zp  = zp_p[0];
    int zpi = (int)rintf(zp);
    unsigned zd = ((unsigned)(zpi & 0xFF)) * 0x01010101u;

    unsigned* rowbase = (unsigned*)(xpad + (size_t)((b * HP + ph) * WP) * CIN);

    if (ph == 0 || ph == HP - 1) {
        for (int j = t; j < WP * CIN / 4; j += 256) rowbase[j] = zd;
        return;
    }
    int h = ph - 1;
    const float* xrow = x + (size_t)b * CIN * H_ * W_ + h * W_;
    int wq = t & 15;
    int cg = t >> 4;
    #pragma unroll
    for (int i = 0; i < 5; ++i) {
        int ci0 = i * 64 + cg * 4;
        float4 f[4];
        #pragma unroll
        for (int jj = 0; jj < 4; ++jj)
            f[jj] = *(const float4*)(xrow + (size_t)(ci0 + jj) * HW_ + wq * 4);
        #pragma unroll
        for (int k = 0; k < 4; ++k) {
            unsigned d = 0;
            #pragma unroll
            for (int jj = 0; jj < 4; ++jj) {
                float v = (&f[jj].x)[k];
                float q = rintf(v * inv) + zp;
                q = fminf(fmaxf(q, -128.0f), 127.0f);
                int qi = (int)q;
                d |= ((unsigned)(qi & 0xFF)) << (8 * jj);
            }
            lds[(wq * 4 + k) * 81 + (ci0 >> 2)] = d;
        }
    }
    __syncthreads();
    if (t < 80)            rowbase[t] = zd;
    else if (t < 160)      rowbase[65 * 80 + (t - 80)] = zd;
    for (int j = t; j < 64 * 80; j += 256) {
        int p = j / 80;
        int d = j - p * 80;
        rowbase[80 + j] = lds[p * 81 + d];
    }
}

// ---------------------------------------------------------------------------
// Kernel 3: implicit-GEMM conv -- SGB-PINNED pipeline + skewed banks.
// Block tile 256(M) x 80(N), 4 waves = 4 M-quarters; wave = 4x5 of 16x16x64.
//
// Round-8 post-mortem: R4-R8 scheduling variants all compiled to ~the same
// emitted loop -- evidence: VGPR_Count=128 < the 172+ live regs the intended
// 3-deep pipeline needs, i.e. the scheduler SINKS loads to their consumers
// (live-range shortening) and collapses the pipeline regardless of source
// structure. Fixes here:
// (1) sched_group_barrier pinning, per tap: [VMEM x5][DS x4][MFMA x20]
//     (tap0: VMEM x12 incl. staging) -- compile-time emission pattern the
//     scheduler satisfies, forcing loads a full MFMA-cluster ahead and
//     forcing the allocator to keep banks live.
// (2) skewed bank refill: at tap tp, B writes bank (tp+2)%3 <- tap tp+2,
//     A writes bank (tp+1)&1 <- tap tp+1. The written bank was consumed at
//     tap tp-1 (not tp) -> one full cluster of WAR slack vs in-flight MFMA
//     source reads; no hazard interlocks.
// Barrier invariant: outstanding vmem at each chunk barrier = 10 (taps 7,8
// cross-chunk B refills); staging (oldest, issued tap0) is drained by the
// compiler's counted wait before tap-8's MFMAs -> s_waitcnt vmcnt(10).
//
// (Round-9 run died to container-level infra failure; kernel re-audited --
// LDS/global bounds exact-fit, uniform barriers, monotone waitcnts, static
// bank indices -- and resubmitted unchanged.)
#define CHUNK_SLOTS 1584           // 6 rows * 66 cols * 4 sub-chunks
#define ROUNDS 7                   // ceil(1584 / 256)
#define BUF_BYTES (ROUNDS * 256 * 16)   // 28,672 B per buffer (25,344 used)

// One chunk's compute. LAST_ must be a literal 0/1; tp is unroll-constant so
// all bank indices are compile-time (rule #20).
#define CHUNK_BODY(c_, LAST_)                                                   \
{                                                                               \
    const int c__ = (c_);                                                       \
    const unsigned char* ab = Al + (c__ & 1) * BUF_BYTES;                       \
    /* chunk-head: A bank0 <- tap0 (4 ds_reads) */                              \
    _Pragma("unroll")                                                           \
    for (int mi = 0; mi < 4; ++mi)                                              \
        aB[0][mi] = *(const v4i*)(ab + wm * 4224 + aoffs[0][mi]);               \
    SGB(0x100, 4, 0);                                                           \
    _Pragma("unroll")                                                           \
    for (int tp = 0; tp < 9; ++tp) {                                            \
        if (!LAST_ && tp == 0) {    /* staging: oldest vmem of the chunk */     \
            unsigned char* dst = Al + ((c__ + 1) & 1) * BUF_BYTES;              \
            int cio = (c__ + 1) * 64;                                           \
            _Pragma("unroll")                                                   \
            for (int r = 0; r < ROUNDS; ++r)                                    \
                __builtin_amdgcn_global_load_lds(                               \
                    (gas_uptr)(const void*)(xpad + srcoff[r] + cio),            \
                    (las_uptr)(dst + r * 4096 + t * 16), 16, 0, 0);             \
        }                                                                       \
        /* B refill: bank (tp+2)%3 <- tap tp+2 (this chunk or next) */          \
        if (tp < 7) {                                                           \
            _Pragma("unroll")                                                   \
            for (int ni = 0; ni < 5; ++ni)                                      \
                bB[(tp + 2) % 3][ni] =                                          \
                    *(const v4i*)(bbase[ni] + ((tp + 2) * 5 + c__) * 1024);     \
        } else if (!LAST_) {                                                    \
            _Pragma("unroll")                                                   \
            for (int ni = 0; ni < 5; ++ni)                                      \
                bB[(tp + 2) % 3][ni] =                                          \
                    *(const v4i*)(bbase[ni] + ((tp - 7) * 5 + (c__ + 1)) * 1024);\
        }                                                                       \
        /* A refill: bank (tp+1)&1 <- tap tp+1 */                               \
        if (tp < 8) {                                                           \
            int tn  = tp + 1;                                                   \
            int kh2 = tn / 3;                                                   \
            int kw2 = tn - kh2 * 3;                                             \
            _Pragma("unroll")                                                   \
            for (int mi = 0; mi < 4; ++mi)                                      \
                aB[(tp + 1) & 1][mi] =                                          \
                    *(const v4i*)(ab + (wm + kh2) * 4224 + aoffs[kw2][mi]);     \
        }                                                                       \
        /* pin emission pattern for this tap: [VMEM][DS][MFMA] */               \
        if (!LAST_ && tp == 0)      SGB(0x20, 12, 0);                           \
        else if (tp < 7 || !LAST_)  SGB(0x20, 5, 0);                            \
        if (tp < 8)                 SGB(0x100, 4, 0);                           \
        SGB(0x8, 20, 0);                                                        \
        __builtin_amdgcn_s_setprio(1);                                          \
        _Pragma("unroll")                                                       \
        for (int mi = 0; mi < 4; ++mi)                                          \
            _Pragma("unroll")                                                   \
            for (int ni = 0; ni < 5; ++ni)                                      \
                acc[mi][ni] = __builtin_amdgcn_mfma_i32_16x16x64_i8(            \
                    aB[tp & 1][mi], bB[tp % 3][ni], acc[mi][ni], 0, 0, 0);      \
        __builtin_amdgcn_s_setprio(0);                                          \
    }                                                                           \
}

__global__ __launch_bounds__(256, 2) void conv_gemm_kernel(const unsigned char* __restrict__ xpad,
                                                           const unsigned char* __restrict__ w8,
                                                           const float* __restrict__ scale,
                                                           const float* __restrict__ be,
                                                           float* __restrict__ out) {
    __shared__ __align__(16) unsigned char Al[2 * BUF_BYTES];   // 57,344 B

    int t    = threadIdx.x;
    int lane = t & 63;
    int wave = t >> 6;
    int wm   = wave;               // M quarter (64 pixels each); all waves share N
    int m0   = blockIdx.x * 256;   // 4 image rows of one batch image
    int n0   = blockIdx.y * 80;
    int b0   = m0 >> 12;
    int h0   = (m0 & 4095) >> 6;   // first output row of this 4-row tile

    // --- staging source offsets: slot = r*256+t -> (R,C,ql); source sub-chunk
    //     pre-swizzled: qs = ql ^ ((C>>1)&3). Slots >= 1584 clamp to slot 0
    //     (dup fetch = L1 hit; garbage lands in dead LDS tail 25344..28671).
    int srcoff[ROUNDS];
    #pragma unroll
    for (int r = 0; r < ROUNDS; ++r) {
        int slot = r * 256 + t;
        if (slot >= CHUNK_SLOTS) slot = 0;
        int R   = slot / 264;                 // 66 cols * 4 sub-chunks per row
        int rem = slot - R * 264;
        int C   = rem >> 2;
        int ql  = rem & 3;
        int qs  = ql ^ ((C >> 1) & 3);
        srcoff[r] = ((b0 * HP + h0 + R) * WP + C) * CIN + qs * 16;
    }

    int colc = lane & 15;
    int q    = lane >> 4;

    // --- A fragment LDS offsets (per kw, per mi); row term (wm+kh)*4224 added
    //     at use (wm 0..3, kh 0..2 -> rows 0..5). Phase-uniform swizzle:
    //     within any 16-lane quarter-wave, slot-group = 4(C&1) + q^((C>>1)&3)
    //     covers all 8 bank-groups exactly twice.
    int aoffs[3][4];
    #pragma unroll
    for (int kw = 0; kw < 3; ++kw)
        #pragma unroll
        for (int mi = 0; mi < 4; ++mi) {
            int C = mi * 16 + colc + kw;
            aoffs[kw][mi] = C * 64 + ((q ^ ((C >> 1) & 3)) * 16);
        }

    // --- B fragment base pointers: fragment-linear w8, one contiguous 1KiB
    //     per (coT, tap, chunk). IDENTICAL across the block's 4 waves.
    const unsigned char* bbase[5];
    int coT0 = n0 >> 4;
    #pragma unroll
    for (int ni = 0; ni < 5; ++ni)
        bbase[ni] = w8 + (size_t)(coT0 + ni) * (45 * 1024) + lane * 16;

    v4i acc[4][5];
    v4i zero = {0, 0, 0, 0};
    #pragma unroll
    for (int mi = 0; mi < 4; ++mi)
        #pragma unroll
        for (int ni = 0; ni < 5; ++ni) acc[mi][ni] = zero;

    // --- prologue: staging FIRST (oldest in vmcnt FIFO), then B banks 0,1
    //     (taps 0,1) -- counted barrier leaves exactly those 10 in flight.
    v4i bB[3][5], aB[2][4];
    #pragma unroll
    for (int r = 0; r < ROUNDS; ++r)
        __builtin_amdgcn_global_load_lds((gas_uptr)(const void*)(xpad + srcoff[r]),
                                         (las_uptr)(Al + r * 4096 + t * 16), 16, 0, 0);
    #pragma unroll
    for (int k = 0; k < 2; ++k)
        #pragma unroll
        for (int ni = 0; ni < 5; ++ni)
            bB[k][ni] = *(const v4i*)(bbase[ni] + (k * 5) * 1024);

    // counted barrier: staging (7 oldest) drained; 10 B loads stay in flight.
    asm volatile("s_waitcnt vmcnt(10)" ::: "memory");
    __builtin_amdgcn_s_barrier();

    #pragma unroll 1
    for (int c = 0; c < 4; ++c) {
        CHUNK_BODY(c, 0)
        // Steady state: outstanding vmem = 10 cross-chunk B refills (taps
        // 7,8); staging (issued tap 0) already drained by tap-8's counted
        // B-wait. vmcnt(10) is ~free; pipeline survives the barrier (T4).
        asm volatile("s_waitcnt vmcnt(10)" ::: "memory");
        __builtin_amdgcn_s_barrier();
    }
    CHUNK_BODY(4, 1)       // peeled: no staging, no cross-chunk B, static guards

    // Epilogue: C/D layout col = lane&15 (co), row = q*4 + reg (pixel).
    #pragma unroll
    for (int ni = 0; ni < 5; ++ni) {
        int co = n0 + ni * 16 + colc;
        float s  = scale[co];
        float bz = be[co];
        #pragma unroll
        for (int mi = 0; mi < 4; ++mi) {
            int pix = m0 + wm * 64 + mi * 16 + q * 4;
            int bb2 = pix >> 12;
            int hw  = pix & 4095;
            v4i v = acc[mi][ni];
            float4 o;
            o.x = s * (float)v.x + bz;
            o.y = s * (float)v.y + bz;
            o.z = s * (float)v.z + bz;
            o.w = s * (float)v.w + bz;
            *(float4*)(out + (size_t)(bb2 * COUT + co) * HW_ + hw) = o;
        }
    }
}

// ---------------------------------------------------------------------------
extern "C" void kernel_launch(void* const* d_in, const int* in_sizes, int n_in,
                              void* d_out, int out_size, void* d_ws, size_t ws_size,
                              hipStream_t stream) {
    const float* x     = (const float*)d_in[0];
    const int*   wint  = (const int*)d_in[1];
    const float* wsum  = (const float*)d_in[2];
    const float* scale = (const float*)d_in[3];
    const float* inv_p = (const float*)d_in[4];
    const float* zp_p  = (const float*)d_in[5];
    const float* bias  = (const float*)d_in[6];
    float* out = (float*)d_out;

    unsigned char* xpad = (unsigned char*)d_ws;
    unsigned char* w8   = xpad + XPAD_BYTES;
    float*         be   = (float*)(w8 + W8_BYTES);

    repack_bias_kernel<<<(COUT * 720) / 256, 256, 0, stream>>>(wint, w8, wsum, scale, bias, zp_p, be);
    quant_pad_kernel<<<B_ * HP, 256, 0, stream>>>(x, xpad, inv_p, zp_p);

    dim3 grid((B_ * H_ * W_) / 256, COUT / 80);       // 128 x 4 = 512 blocks
    conv_gemm_kernel<<<grid, 256, 0, stream>>>(xpad, w8, scale, be, out);
}